// Round 1
// 1048.265 us; speedup vs baseline: 1.0131x; 1.0131x over previous
//
#include <hip/hip_runtime.h>
#include <math.h>

#define NN 100000
#define NE 3200000
#define NF 512
#define NH 256
#define NC 64
#define KSTEPS 10
#define NB 391        // ceil(NN/256)
#define CAP 96        // max real edges per node (Poisson λ=32 → P(>96) ≈ 1e-19)
#define NPH 8         // fill phases (dst ranges of 12500 nodes) == number of XCDs
#define FBP 1024      // fill blocks per phase

typedef _Float16 half8 __attribute__((ext_vector_type(8)));
typedef _Float16 h4v  __attribute__((ext_vector_type(4)));
typedef float f32x4 __attribute__((ext_vector_type(4)));

// ---------------- init: cnt=0, zero-node rows of y buffers ----------------

__global__ __launch_bounds__(256) void init_k(int* cnt, _Float16* y0, _Float16* yA, _Float16* yB) {
  int i = blockIdx.x * 256 + threadIdx.x;
  if (i < NN) cnt[i] = 0;
  if (blockIdx.x == 0) {
    int t = threadIdx.x;
    if (t < 64)       y0[(size_t)NN * NC + t] = (_Float16)0.f;
    else if (t < 128) yA[(size_t)NN * NC + (t - 64)] = (_Float16)0.f;
    else if (t < 192) yB[(size_t)NN * NC + (t - 128)] = (_Float16)0.f;
  }
}

// ---------------- single-pass slot fill ----------------
// phase = blockIdx & 7: with the round-robin blockIdx->XCD mapping (XCD = bid%8),
// ALL blocks resident on XCD p handle dst range p. Scatter writes to slot
// region p (touched-line footprint ~2MB) then stay in that XCD's private L2
// until lines are full, instead of 8 XCDs each writing back partial copies
// of the same lines (was 197MB WRITE_SIZE for a 12.8MB payload).

__global__ __launch_bounds__(256) void fill_k(const int* __restrict__ dstI, const int* __restrict__ srcI,
                                              int* __restrict__ cnt, int* __restrict__ slots) {
  int ph = blockIdx.x & 7;        // phase == XCD id (bijection, NPH==8)
  int bi = blockIdx.x >> 3;
  int lo = ph * (NN / NPH);
  int hi = lo + (NN / NPH);
  for (int e = bi * 256 + threadIdx.x; e < NE; e += FBP * 256) {
    int d = dstI[e];
    if (d >= lo && d < hi) {
      int pos = atomicAdd(&cnt[d], 1);
      if (pos < CAP) slots[(size_t)d * CAP + pos] = srcI[e];
    }
  }
}

// pad each row from cnt to its 16-aligned end with the zero-node index NN
__global__ __launch_bounds__(256) void pad_k(const int* __restrict__ cnt, int* __restrict__ slots) {
  int d = blockIdx.x * 256 + threadIdx.x;
  if (d >= NN) return;
  int c = cnt[d];
  int e = (c + 15) & ~15;
  for (int p = c; p < e; ++p) slots[(size_t)d * CAP + p] = NN;
}

// deg = cnt+1 (self-loop): dinv, sqrt(deg), 0.9/deg
__global__ __launch_bounds__(256) void dinv_k(const int* __restrict__ cnt, float* dinv, float* dsqrt, float* amul) {
  int i = blockIdx.x * 256 + threadIdx.x;
  if (i < NN) {
    float d = (float)(cnt[i] + 1);
    dinv[i]  = rsqrtf(d);
    dsqrt[i] = sqrtf(d);
    amul[i]  = 0.9f / d;
  }
}

// ---------------- weight transpose + fp16 convert ----------------

__global__ __launch_bounds__(256) void cvtW1T_k(const float* __restrict__ W1, _Float16* __restrict__ W1T) {
  int t = blockIdx.x * 256 + threadIdx.x;            // 131072
  int n = t >> 9, k = t & 511;
  W1T[t] = (_Float16)W1[k * NH + n];                 // W1T[n][k] = W1[k][n]
}

__global__ __launch_bounds__(256) void cvtW2T_k(const float* __restrict__ W2, _Float16* __restrict__ W2T) {
  int t = blockIdx.x * 256 + threadIdx.x;            // 16384
  int n = t >> 8, k = t & 255;
  W2T[t] = (_Float16)W2[k * NC + n];                 // W2T[n][k] = W2[k][n]
}

// ---------------- fused 2-layer MLP via f16 MFMA ----------------
// outputs y0 = dinv*h0 and c0 = 0.1*dinv*h0 (both fp16, node-major)

__global__ __launch_bounds__(256) void mlp_k(const float* __restrict__ x, const _Float16* __restrict__ W1T,
                                             const float* __restrict__ b1, const _Float16* __restrict__ W2T,
                                             const float* __restrict__ b2, const float* __restrict__ dinv,
                                             _Float16* __restrict__ y0, _Float16* __restrict__ c0) {
  __shared__ _Float16 smem[16896];          // 33792 B
  _Float16* As = smem;                      // [64][40]
  _Float16* Bs = smem + 64 * 40;            // [256][40]
  _Float16* Hs = smem;                      // [64][264] (reuses As/Bs space)

  const int t    = threadIdx.x;
  const int wave = t >> 6;
  const int lane = t & 63;
  const int l15  = lane & 15;
  const int q    = lane >> 4;
  const int m0   = blockIdx.x * 64;

  f32x4 acc[4][4] = {};

  for (int kk = 0; kk < NF; kk += 32) {
    __syncthreads();                        // prev-iter LDS reads done before overwrite
    { // stage A: x[m0..m0+64)[kk..kk+32) -> fp16 As
      int row = t >> 2;
      int kq  = (t & 3) << 3;
      int gr  = m0 + row;
      float4 v0 = make_float4(0.f, 0.f, 0.f, 0.f), v1 = v0;
      if (gr < NN) {
        const float* xp = &x[(size_t)gr * NF + kk + kq];
        v0 = *(const float4*)xp;
        v1 = *(const float4*)(xp + 4);
      }
      half8 hv;
      hv[0] = (_Float16)v0.x; hv[1] = (_Float16)v0.y; hv[2] = (_Float16)v0.z; hv[3] = (_Float16)v0.w;
      hv[4] = (_Float16)v1.x; hv[5] = (_Float16)v1.y; hv[6] = (_Float16)v1.z; hv[7] = (_Float16)v1.w;
      *(half8*)&As[row * 40 + kq] = hv;
    }
    // stage B: W1T[0..256)[kk..kk+32) -> Bs
    #pragma unroll
    for (int i = 0; i < 4; ++i) {
      int idx = t + (i << 8);
      int n   = idx >> 2;
      int kq  = (idx & 3) << 3;
      *(half8*)&Bs[n * 40 + kq] = *(const half8*)&W1T[(size_t)n * NF + kk + kq];
    }
    __syncthreads();
    half8 af[4], bf[4];
    #pragma unroll
    for (int mi = 0; mi < 4; ++mi) af[mi] = *(half8*)&As[(mi * 16 + l15) * 40 + q * 8];
    #pragma unroll
    for (int ni = 0; ni < 4; ++ni) bf[ni] = *(half8*)&Bs[(wave * 64 + ni * 16 + l15) * 40 + q * 8];
    #pragma unroll
    for (int mi = 0; mi < 4; ++mi)
      #pragma unroll
      for (int ni = 0; ni < 4; ++ni)
        acc[mi][ni] = __builtin_amdgcn_mfma_f32_16x16x32_f16(af[mi], bf[ni], acc[mi][ni], 0, 0, 0);
  }
  __syncthreads();   // all As/Bs reads complete -> safe to reuse as Hs

  // epilogue 1: bias + relu -> Hs fp16  (C/D: col=lane&15, row=q*4+reg)
  #pragma unroll
  for (int mi = 0; mi < 4; ++mi) {
    #pragma unroll
    for (int ni = 0; ni < 4; ++ni) {
      int ch = wave * 64 + ni * 16 + l15;
      float bb = b1[ch];
      #pragma unroll
      for (int r = 0; r < 4; ++r) {
        int m = mi * 16 + q * 4 + r;
        float v = acc[mi][ni][r] + bb;
        Hs[m * 264 + ch] = (_Float16)(v > 0.f ? v : 0.f);
      }
    }
  }
  __syncthreads();

  // GEMM2: h0[64x64] = Hs[64x256] @ W2 (+b2); wave w -> cols [16w, 16w+16)
  f32x4 acc2[4] = {};
  for (int kt = 0; kt < 8; ++kt) {
    half8 bf2 = *(const half8*)&W2T[(size_t)(wave * 16 + l15) * NH + kt * 32 + q * 8];
    #pragma unroll
    for (int mi = 0; mi < 4; ++mi) {
      half8 af2 = *(half8*)&Hs[(mi * 16 + l15) * 264 + kt * 32 + q * 8];
      acc2[mi] = __builtin_amdgcn_mfma_f32_16x16x32_f16(af2, bf2, acc2[mi], 0, 0, 0);
    }
  }
  int c = wave * 16 + l15;
  float bb2 = b2[c];
  #pragma unroll
  for (int mi = 0; mi < 4; ++mi)
    #pragma unroll
    for (int r = 0; r < 4; ++r) {
      int m = m0 + mi * 16 + q * 4 + r;
      if (m < NN) {
        float hv = acc2[mi][r] + bb2;
        float dv = dinv[m];
        y0[(size_t)m * NC + c] = (_Float16)(dv * hv);
        c0[(size_t)m * NC + c] = (_Float16)(0.1f * dv * hv);
      }
    }
}

// ---------------- APPNP propagation step on y = dinv*h ----------------
// one wave per node. Quarter-wave (16 lanes x 8B) covers one 128B row ->
// 4 edges per gather instruction; packed fp16 accumulation (v_pk_add_f16);
// 32-bit mad addressing. Slot rows 16-padded with zero-node NN.

__global__ __launch_bounds__(256) void appnp_k(const _Float16* __restrict__ y_in, const _Float16* __restrict__ c0,
                                               _Float16* __restrict__ y_out,
                                               const int* __restrict__ cnt, const int* __restrict__ slots,
                                               const float* __restrict__ amul) {
  const int lane = threadIdx.x & 63;
  const int qw   = lane >> 4;          // edge sub-slot within group of 4
  const int fq   = lane & 15;          // feature quad: feats 4*fq .. 4*fq+3
  int node = blockIdx.x * 4 + (threadIdx.x >> 6);
  node = __builtin_amdgcn_readfirstlane(node);   // wave-uniform
  const int pcnt = (cnt[node] + 15) & ~15;
  const int* row = slots + (size_t)node * CAP;
  const char* yb = (const char*)y_in;
  const unsigned foff = (unsigned)fq * 8u;

  h4v acc = { (_Float16)0.f, (_Float16)0.f, (_Float16)0.f, (_Float16)0.f };
  for (int e = 0; e < pcnt; e += 16) {
    #pragma unroll
    for (int j = 0; j < 4; ++j) {
      int idx = row[e + j * 4 + qw];                       // 16B line per wave, L1/L2 hit
      unsigned off = (unsigned)idx * 128u + foff;          // v_mad_u32_u24
      acc += *(const h4v*)(yb + off);                      // dwordx2 gather + 2x v_pk_add_f16
    }
  }

  // reduce across the 4 quarter-waves (lanes with same fq)
  int2 ai = *(int2*)&acc;
  int2 o1; o1.x = __shfl_xor(ai.x, 16, 64); o1.y = __shfl_xor(ai.y, 16, 64);
  acc += *(h4v*)&o1;
  ai = *(int2*)&acc;
  int2 o2; o2.x = __shfl_xor(ai.x, 32, 64); o2.y = __shfl_xor(ai.y, 32, 64);
  acc += *(h4v*)&o2;

  if (qw == 0) {
    // self-loop + c0 + amul scale, in fp32
    size_t rowb = (size_t)node * 128 + foff;
    h4v self = *(const h4v*)((const char*)y_in + rowb);
    h4v cc   = *(const h4v*)((const char*)c0   + rowb);
    float am = amul[node];
    h4v r;
    #pragma unroll
    for (int i = 0; i < 4; ++i)
      r[i] = (_Float16)(am * ((float)acc[i] + (float)self[i]) + (float)cc[i]);
    *(h4v*)((char*)y_out + rowb) = r;
  }
}

// ---------------- log_softmax (recover h = y * sqrt(deg)) ----------------

__global__ __launch_bounds__(256) void lsm_k(const _Float16* __restrict__ y, const float* __restrict__ dsqrt,
                                             float* __restrict__ out) {
  int lane = threadIdx.x & 63;
  int node = blockIdx.x * 4 + (threadIdx.x >> 6);
  node = __builtin_amdgcn_readfirstlane(node);
  float v = (float)y[(size_t)node * NC + lane] * dsqrt[node];
  float m = v;
  #pragma unroll
  for (int off = 32; off > 0; off >>= 1) m = fmaxf(m, __shfl_xor(m, off, 64));
  float e = expf(v - m);
  float s = e;
  #pragma unroll
  for (int off = 32; off > 0; off >>= 1) s += __shfl_xor(s, off, 64);
  out[(size_t)node * NC + lane] = (v - m) - logf(s);
}

// ---------------- launch ----------------

extern "C" void kernel_launch(void* const* d_in, const int* in_sizes, int n_in,
                              void* d_out, int out_size, void* d_ws, size_t ws_size,
                              hipStream_t stream) {
  (void)in_sizes; (void)n_in; (void)out_size; (void)ws_size;
  const float* x  = (const float*)d_in[0];
  const int*   ei = (const int*)d_in[1];
  const float* W1 = (const float*)d_in[2];
  const float* b1 = (const float*)d_in[3];
  const float* W2 = (const float*)d_in[4];
  const float* b2 = (const float*)d_in[5];
  float* out = (float*)d_out;

  const int* srcI = ei;        // edge_index[0] = message source
  const int* dstI = ei + NE;   // edge_index[1] = aggregation target

  char* p = (char*)d_ws;
  auto carve = [&](size_t bytes) -> void* {
    void* q = (void*)p;
    p += (bytes + 255) & ~(size_t)255;
    return q;
  };
  _Float16* y0   = (_Float16*)carve((size_t)(NN + 1) * NC * 2);
  _Float16* yA   = (_Float16*)carve((size_t)(NN + 1) * NC * 2);
  _Float16* yB   = (_Float16*)carve((size_t)(NN + 1) * NC * 2);
  _Float16* c0   = (_Float16*)carve((size_t)NN * NC * 2);
  _Float16* W1T  = (_Float16*)carve((size_t)NH * NF * 2);
  _Float16* W2T  = (_Float16*)carve((size_t)NC * NH * 2);
  float* dinv    = (float*)carve((size_t)NN * 4);
  float* dsqrt   = (float*)carve((size_t)NN * 4);
  float* amul    = (float*)carve((size_t)NN * 4);
  int*   cnt     = (int*)carve((size_t)NN * 4);
  int*   slots   = (int*)carve((size_t)NN * CAP * 4);

  init_k   <<<NB, 256, 0, stream>>>(cnt, y0, yA, yB);
  fill_k   <<<NPH * FBP, 256, 0, stream>>>(dstI, srcI, cnt, slots);
  pad_k    <<<NB, 256, 0, stream>>>(cnt, slots);
  dinv_k   <<<NB, 256, 0, stream>>>(cnt, dinv, dsqrt, amul);
  cvtW1T_k <<<(NH * NF) / 256, 256, 0, stream>>>(W1, W1T);
  cvtW2T_k <<<(NC * NH) / 256, 256, 0, stream>>>(W2, W2T);
  mlp_k    <<<(NN + 63) / 64, 256, 0, stream>>>(x, W1T, b1, W2T, b2, dinv, y0, c0);

  const _Float16* yin = y0;
  _Float16* bufs[2] = { yA, yB };
  for (int it = 0; it < KSTEPS; ++it) {
    _Float16* yo = bufs[it & 1];
    appnp_k<<<NN / 4, 256, 0, stream>>>(yin, c0, yo, cnt, slots, amul);
    yin = yo;
  }
  lsm_k<<<NN / 4, 256, 0, stream>>>(yin, dsqrt, out);
}

// Round 3
// 1036.597 us; speedup vs baseline: 1.0245x; 1.0113x over previous
//
#include <hip/hip_runtime.h>
#include <math.h>

#define NN 100000
#define NE 3200000
#define NF 512
#define NH 256
#define NC 64
#define KSTEPS 10
#define NB 391        // ceil(NN/256)
#define CAP 96        // max real edges per node (Poisson λ=32 → P(>96) ≈ 1e-19)
#define NPH 8         // fill phases (dst ranges of 12500 nodes) == number of XCDs
#define FBP 1024      // fill blocks per phase

typedef _Float16 half8 __attribute__((ext_vector_type(8)));
typedef _Float16 h4v  __attribute__((ext_vector_type(4)));
typedef _Float16 h8v  __attribute__((ext_vector_type(8)));
typedef float f32x4 __attribute__((ext_vector_type(4)));

// ---------------- init: cnt=0, zero-node rows of y buffers ----------------

__global__ __launch_bounds__(256) void init_k(int* cnt, _Float16* y0, _Float16* yA, _Float16* yB) {
  int i = blockIdx.x * 256 + threadIdx.x;
  if (i < NN) cnt[i] = 0;
  if (blockIdx.x == 0) {
    int t = threadIdx.x;
    if (t < 64)       y0[(size_t)NN * NC + t] = (_Float16)0.f;
    else if (t < 128) yA[(size_t)NN * NC + (t - 64)] = (_Float16)0.f;
    else if (t < 192) yB[(size_t)NN * NC + (t - 128)] = (_Float16)0.f;
  }
}

// ---------------- single-pass slot fill ----------------
// phase = blockIdx & 7 (== XCD id under the round-robin blockIdx->XCD map):
// all blocks on XCD p handle dst range p, so scatter writes are confined to
// a ~1.6MB dirty-line footprint in that XCD's L2. The dst/src edge streams
// are read NON-TEMPORALLY so the 25.6MB/phase stream does not LRU-evict the
// partially-filled dirty slot lines (R1 counters: WRITE_SIZE 169MB for a
// 12.8MB payload = ~13x amplification caused by that eviction).

__global__ __launch_bounds__(256) void fill_k(const int* __restrict__ dstI, const int* __restrict__ srcI,
                                              int* __restrict__ cnt, int* __restrict__ slots) {
  int ph = blockIdx.x & 7;        // phase == XCD id (bijection, NPH==8)
  int bi = blockIdx.x >> 3;
  int lo = ph * (NN / NPH);
  int hi = lo + (NN / NPH);
  for (int e = bi * 256 + threadIdx.x; e < NE; e += FBP * 256) {
    int d = __builtin_nontemporal_load(&dstI[e]);
    if (d >= lo && d < hi) {
      int s = __builtin_nontemporal_load(&srcI[e]);
      int pos = atomicAdd(&cnt[d], 1);
      if (pos < CAP) slots[(size_t)d * CAP + pos] = s;
    }
  }
}

// pad each row from cnt to its 16-aligned end with the zero-node index NN
__global__ __launch_bounds__(256) void pad_k(const int* __restrict__ cnt, int* __restrict__ slots) {
  int d = blockIdx.x * 256 + threadIdx.x;
  if (d >= NN) return;
  int c = cnt[d];
  int e = (c + 15) & ~15;
  for (int p = c; p < e; ++p) slots[(size_t)d * CAP + p] = NN;
}

// deg = cnt+1 (self-loop): dinv, sqrt(deg), 0.9/deg
__global__ __launch_bounds__(256) void dinv_k(const int* __restrict__ cnt, float* dinv, float* dsqrt, float* amul) {
  int i = blockIdx.x * 256 + threadIdx.x;
  if (i < NN) {
    float d = (float)(cnt[i] + 1);
    dinv[i]  = rsqrtf(d);
    dsqrt[i] = sqrtf(d);
    amul[i]  = 0.9f / d;
  }
}

// ---------------- weight transpose + fp16 convert ----------------

__global__ __launch_bounds__(256) void cvtW1T_k(const float* __restrict__ W1, _Float16* __restrict__ W1T) {
  int t = blockIdx.x * 256 + threadIdx.x;            // 131072
  int n = t >> 9, k = t & 511;
  W1T[t] = (_Float16)W1[k * NH + n];                 // W1T[n][k] = W1[k][n]
}

__global__ __launch_bounds__(256) void cvtW2T_k(const float* __restrict__ W2, _Float16* __restrict__ W2T) {
  int t = blockIdx.x * 256 + threadIdx.x;            // 16384
  int n = t >> 8, k = t & 255;
  W2T[t] = (_Float16)W2[k * NC + n];                 // W2T[n][k] = W2[k][n]
}

// ---------------- fused 2-layer MLP via f16 MFMA ----------------
// outputs y0 = dinv*h0 and c0 = 0.1*dinv*h0 (both fp16, node-major)

__global__ __launch_bounds__(256) void mlp_k(const float* __restrict__ x, const _Float16* __restrict__ W1T,
                                             const float* __restrict__ b1, const _Float16* __restrict__ W2T,
                                             const float* __restrict__ b2, const float* __restrict__ dinv,
                                             _Float16* __restrict__ y0, _Float16* __restrict__ c0) {
  __shared__ _Float16 smem[16896];          // 33792 B
  _Float16* As = smem;                      // [64][40]
  _Float16* Bs = smem + 64 * 40;            // [256][40]
  _Float16* Hs = smem;                      // [64][264] (reuses As/Bs space)

  const int t    = threadIdx.x;
  const int wave = t >> 6;
  const int lane = t & 63;
  const int l15  = lane & 15;
  const int q    = lane >> 4;
  const int m0   = blockIdx.x * 64;

  f32x4 acc[4][4] = {};

  for (int kk = 0; kk < NF; kk += 32) {
    __syncthreads();                        // prev-iter LDS reads done before overwrite
    { // stage A: x[m0..m0+64)[kk..kk+32) -> fp16 As
      int row = t >> 2;
      int kq  = (t & 3) << 3;
      int gr  = m0 + row;
      float4 v0 = make_float4(0.f, 0.f, 0.f, 0.f), v1 = v0;
      if (gr < NN) {
        const float* xp = &x[(size_t)gr * NF + kk + kq];
        v0 = *(const float4*)xp;
        v1 = *(const float4*)(xp + 4);
      }
      half8 hv;
      hv[0] = (_Float16)v0.x; hv[1] = (_Float16)v0.y; hv[2] = (_Float16)v0.z; hv[3] = (_Float16)v0.w;
      hv[4] = (_Float16)v1.x; hv[5] = (_Float16)v1.y; hv[6] = (_Float16)v1.z; hv[7] = (_Float16)v1.w;
      *(half8*)&As[row * 40 + kq] = hv;
    }
    // stage B: W1T[0..256)[kk..kk+32) -> Bs
    #pragma unroll
    for (int i = 0; i < 4; ++i) {
      int idx = t + (i << 8);
      int n   = idx >> 2;
      int kq  = (idx & 3) << 3;
      *(half8*)&Bs[n * 40 + kq] = *(const half8*)&W1T[(size_t)n * NF + kk + kq];
    }
    __syncthreads();
    half8 af[4], bf[4];
    #pragma unroll
    for (int mi = 0; mi < 4; ++mi) af[mi] = *(half8*)&As[(mi * 16 + l15) * 40 + q * 8];
    #pragma unroll
    for (int ni = 0; ni < 4; ++ni) bf[ni] = *(half8*)&Bs[(wave * 64 + ni * 16 + l15) * 40 + q * 8];
    #pragma unroll
    for (int mi = 0; mi < 4; ++mi)
      #pragma unroll
      for (int ni = 0; ni < 4; ++ni)
        acc[mi][ni] = __builtin_amdgcn_mfma_f32_16x16x32_f16(af[mi], bf[ni], acc[mi][ni], 0, 0, 0);
  }
  __syncthreads();   // all As/Bs reads complete -> safe to reuse as Hs

  // epilogue 1: bias + relu -> Hs fp16  (C/D: col=lane&15, row=q*4+reg)
  #pragma unroll
  for (int mi = 0; mi < 4; ++mi) {
    #pragma unroll
    for (int ni = 0; ni < 4; ++ni) {
      int ch = wave * 64 + ni * 16 + l15;
      float bb = b1[ch];
      #pragma unroll
      for (int r = 0; r < 4; ++r) {
        int m = mi * 16 + q * 4 + r;
        float v = acc[mi][ni][r] + bb;
        Hs[m * 264 + ch] = (_Float16)(v > 0.f ? v : 0.f);
      }
    }
  }
  __syncthreads();

  // GEMM2: h0[64x64] = Hs[64x256] @ W2 (+b2); wave w -> cols [16w, 16w+16)
  f32x4 acc2[4] = {};
  for (int kt = 0; kt < 8; ++kt) {
    half8 bf2 = *(const half8*)&W2T[(size_t)(wave * 16 + l15) * NH + kt * 32 + q * 8];
    #pragma unroll
    for (int mi = 0; mi < 4; ++mi) {
      half8 af2 = *(half8*)&Hs[(mi * 16 + l15) * 264 + kt * 32 + q * 8];
      acc2[mi] = __builtin_amdgcn_mfma_f32_16x16x32_f16(af2, bf2, acc2[mi], 0, 0, 0);
    }
  }
  int c = wave * 16 + l15;
  float bb2 = b2[c];
  #pragma unroll
  for (int mi = 0; mi < 4; ++mi)
    #pragma unroll
    for (int r = 0; r < 4; ++r) {
      int m = m0 + mi * 16 + q * 4 + r;
      if (m < NN) {
        float hv = acc2[mi][r] + bb2;
        float dv = dinv[m];
        y0[(size_t)m * NC + c] = (_Float16)(dv * hv);
        c0[(size_t)m * NC + c] = (_Float16)(0.1f * dv * hv);
      }
    }
}

// ---------------- APPNP propagation step on y = dinv*h ----------------
// one wave per node. Eighth-wave (8 lanes x 16B) covers one 128B row ->
// 8 edges per gather instruction (dwordx4, was 4 edges/dwordx2); packed
// fp16 accumulation; slot rows 16-padded with zero-node NN.

__global__ __launch_bounds__(256) void appnp_k(const _Float16* __restrict__ y_in, const _Float16* __restrict__ c0,
                                               _Float16* __restrict__ y_out,
                                               const int* __restrict__ cnt, const int* __restrict__ slots,
                                               const float* __restrict__ amul) {
  const int lane = threadIdx.x & 63;
  const int g    = lane >> 3;          // edge sub-slot within group of 8
  const int fc   = lane & 7;           // feature chunk: feats 8*fc .. 8*fc+7
  int node = blockIdx.x * 4 + (threadIdx.x >> 6);
  node = __builtin_amdgcn_readfirstlane(node);   // wave-uniform
  const int pcnt = (cnt[node] + 15) & ~15;
  const int* row = slots + (size_t)node * CAP;
  const char* yb = (const char*)y_in;
  const unsigned foff = (unsigned)fc * 16u;

  h8v acc = { (_Float16)0.f, (_Float16)0.f, (_Float16)0.f, (_Float16)0.f,
              (_Float16)0.f, (_Float16)0.f, (_Float16)0.f, (_Float16)0.f };
  for (int e = 0; e < pcnt; e += 16) {
    #pragma unroll
    for (int j = 0; j < 2; ++j) {
      int idx = row[e + j * 8 + g];                        // 32B line per wave, broadcast per group
      unsigned off = (unsigned)idx * 128u + foff;          // v_mad_u32_u24
      acc += *(const h8v*)(yb + off);                      // dwordx4 gather + 4x v_pk_add_f16
    }
  }

  // reduce across the 8 groups (lanes with same fc): xor 8, 16, 32
  #pragma unroll
  for (int d = 8; d <= 32; d <<= 1) {
    int4 ai = *(int4*)&acc;
    int4 o;
    o.x = __shfl_xor(ai.x, d, 64);
    o.y = __shfl_xor(ai.y, d, 64);
    o.z = __shfl_xor(ai.z, d, 64);
    o.w = __shfl_xor(ai.w, d, 64);
    acc += *(h8v*)&o;
  }

  if (g == 0) {
    // self-loop + c0 + amul scale, in fp32
    size_t rowb = (size_t)node * 128 + foff;
    h8v self = *(const h8v*)((const char*)y_in + rowb);
    h8v cc   = *(const h8v*)((const char*)c0   + rowb);
    float am = amul[node];
    h8v r;
    #pragma unroll
    for (int i = 0; i < 8; ++i)
      r[i] = (_Float16)(am * ((float)acc[i] + (float)self[i]) + (float)cc[i]);
    *(h8v*)((char*)y_out + rowb) = r;
  }
}

// ---------------- log_softmax (recover h = y * sqrt(deg)) ----------------

__global__ __launch_bounds__(256) void lsm_k(const _Float16* __restrict__ y, const float* __restrict__ dsqrt,
                                             float* __restrict__ out) {
  int lane = threadIdx.x & 63;
  int node = blockIdx.x * 4 + (threadIdx.x >> 6);
  node = __builtin_amdgcn_readfirstlane(node);
  float v = (float)y[(size_t)node * NC + lane] * dsqrt[node];
  float m = v;
  #pragma unroll
  for (int off = 32; off > 0; off >>= 1) m = fmaxf(m, __shfl_xor(m, off, 64));
  float e = expf(v - m);
  float s = e;
  #pragma unroll
  for (int off = 32; off > 0; off >>= 1) s += __shfl_xor(s, off, 64);
  out[(size_t)node * NC + lane] = (v - m) - logf(s);
}

// ---------------- launch ----------------

extern "C" void kernel_launch(void* const* d_in, const int* in_sizes, int n_in,
                              void* d_out, int out_size, void* d_ws, size_t ws_size,
                              hipStream_t stream) {
  (void)in_sizes; (void)n_in; (void)out_size; (void)ws_size;
  const float* x  = (const float*)d_in[0];
  const int*   ei = (const int*)d_in[1];
  const float* W1 = (const float*)d_in[2];
  const float* b1 = (const float*)d_in[3];
  const float* W2 = (const float*)d_in[4];
  const float* b2 = (const float*)d_in[5];
  float* out = (float*)d_out;

  const int* srcI = ei;        // edge_index[0] = message source
  const int* dstI = ei + NE;   // edge_index[1] = aggregation target

  char* p = (char*)d_ws;
  auto carve = [&](size_t bytes) -> void* {
    void* q = (void*)p;
    p += (bytes + 255) & ~(size_t)255;
    return q;
  };
  _Float16* y0   = (_Float16*)carve((size_t)(NN + 1) * NC * 2);
  _Float16* yA   = (_Float16*)carve((size_t)(NN + 1) * NC * 2);
  _Float16* yB   = (_Float16*)carve((size_t)(NN + 1) * NC * 2);
  _Float16* c0   = (_Float16*)carve((size_t)NN * NC * 2);
  _Float16* W1T  = (_Float16*)carve((size_t)NH * NF * 2);
  _Float16* W2T  = (_Float16*)carve((size_t)NC * NH * 2);
  float* dinv    = (float*)carve((size_t)NN * 4);
  float* dsqrt   = (float*)carve((size_t)NN * 4);
  float* amul    = (float*)carve((size_t)NN * 4);
  int*   cnt     = (int*)carve((size_t)NN * 4);
  int*   slots   = (int*)carve((size_t)NN * CAP * 4);

  init_k   <<<NB, 256, 0, stream>>>(cnt, y0, yA, yB);
  fill_k   <<<NPH * FBP, 256, 0, stream>>>(dstI, srcI, cnt, slots);
  pad_k    <<<NB, 256, 0, stream>>>(cnt, slots);
  dinv_k   <<<NB, 256, 0, stream>>>(cnt, dinv, dsqrt, amul);
  cvtW1T_k <<<(NH * NF) / 256, 256, 0, stream>>>(W1, W1T);
  cvtW2T_k <<<(NC * NH) / 256, 256, 0, stream>>>(W2, W2T);
  mlp_k    <<<(NN + 63) / 64, 256, 0, stream>>>(x, W1T, b1, W2T, b2, dinv, y0, c0);

  const _Float16* yin = y0;
  _Float16* bufs[2] = { yA, yB };
  for (int it = 0; it < KSTEPS; ++it) {
    _Float16* yo = bufs[it & 1];
    appnp_k<<<NN / 4, 256, 0, stream>>>(yin, c0, yo, cnt, slots, amul);
    yin = yo;
  }
  lsm_k<<<NN / 4, 256, 0, stream>>>(yin, dsqrt, out);
}